// Round 10
// baseline (241.367 us; speedup 1.0000x reference)
//
#include <hip/hip_runtime.h>
#include <hip/hip_bf16.h>

typedef __attribute__((ext_vector_type(4))) short bf16x4;
typedef __attribute__((ext_vector_type(8))) short bf16x8;
typedef __attribute__((ext_vector_type(4))) float f32x4;

#define MFMA32(A,B,C) __builtin_amdgcn_mfma_f32_16x16x32_bf16(A,B,C,0,0,0)
#define ROWB 528   // LDS row pitch: 512B data + 16B pad -> bank-spread, affine addressing

__device__ __forceinline__ short f2bf(float f) {
    __hip_bfloat16 h = __float2bfloat16(f);
    union { __hip_bfloat16 h; short s; } u; u.h = h;
    return u.s;
}

// One-time: transpose+convert weights to bf16.  wqkvT[768][256], wprojT[256][256]
__global__ void prep_weights(const float* __restrict__ wqkv,
                             const float* __restrict__ wproj,
                             short* __restrict__ wqkvT,
                             short* __restrict__ wprojT) {
    const int n = blockIdx.x, k = threadIdx.x;
    if (n < 768) wqkvT[n * 256 + k] = f2bf(wqkv[k * 768 + n]);
    else         wprojT[(n - 768) * 256 + k] = f2bf(wproj[k * 256 + (n - 768)]);
}

// 4-wave block = 1 window; each wave owns 2 heads (sequential) + 64 proj cols.
__launch_bounds__(256, 3)
__global__ void winattn_fused(const float* __restrict__ x,
                              const float* __restrict__ bqkv,
                              const float* __restrict__ bproj,
                              const short* __restrict__ wqkvT,
                              const short* __restrict__ wprojT,
                              float* __restrict__ out) {
    __shared__ char smem[64 * ROWB];   // 33792 B; xw tile, later reused as concat buffer
    const int tid = threadIdx.x;
    const int wid = blockIdx.x;
    const int b  = wid >> 6;
    const int wh = (wid >> 3) & 7;
    const int ww = wid & 7;

    // ---------- Phase 1: stage rolled window -> LDS bf16, linear [64][ROWB] ----------
    {
        const int r   = tid >> 2;                 // 0..63
        const int qtr = tid & 3;                  // 64 floats (128B bf16) per thread
        char* dst = smem + r * ROWB + qtr * 128;
        if (r < 49) {
            const int i = r / 7, j = r - i * 7;
            int h  = wh * 7 + i + 3; if (h  >= 56) h  -= 56;
            int wc = ww * 7 + j + 3; if (wc >= 56) wc -= 56;
            const float* src = x + (((size_t)(b * 56 + h)) * 56 + wc) * 256 + qtr * 64;
            #pragma unroll
            for (int c = 0; c < 8; ++c) {
                f32x4 f0 = *(const f32x4*)(src + c * 8);
                f32x4 f1 = *(const f32x4*)(src + c * 8 + 4);
                bf16x8 o;
                #pragma unroll
                for (int q = 0; q < 4; ++q) { o[q] = f2bf(f0[q]); o[q + 4] = f2bf(f1[q]); }
                *(bf16x8*)(dst + c * 16) = o;
            }
        } else {
            bf16x8 z;
            #pragma unroll
            for (int q = 0; q < 8; ++q) z[q] = 0;
            #pragma unroll
            for (int c = 0; c < 8; ++c) *(bf16x8*)(dst + c * 16) = z;
        }
    }
    __syncthreads();

    const int wv4 = tid >> 6;     // wave 0..3
    const int l   = tid & 63;
    const int l15 = l & 15;
    const int l4  = l >> 4;

    const char* xb[4];
    #pragma unroll
    for (int t = 0; t < 4; ++t) xb[t] = smem + (t * 16 + l15) * ROWB + (l4 << 4);

    // O outputs for both heads parked in registers until the concat barrier
    bf16x4 oreg[2][4][2];          // [hh][q-tile][ch-half]

    // ---------- Phase 2+3 per head: MERGED q/k/v pass (xf read once) -> attention ----------
    #pragma unroll
    for (int hh = 0; hh < 2; ++hh) {
        const int head = (hh << 2) + wv4;
        const short* wB = wqkvT + ((head << 5) << 8);      // q block; +256<<8 k; +512<<8 v
        const int rowoff = l15 * 256 + (l4 << 3);

        f32x4 aq[2][4], ak[2][4], av[4][2];
        #pragma unroll
        for (int h = 0; h < 2; ++h)
            #pragma unroll
            for (int t = 0; t < 4; ++t) {
                aq[h][t] = (f32x4){0.f, 0.f, 0.f, 0.f};
                ak[h][t] = (f32x4){0.f, 0.f, 0.f, 0.f};
                av[t][h] = (f32x4){0.f, 0.f, 0.f, 0.f};
            }

        #pragma unroll
        for (int kk = 0; kk < 8; ++kk) {
            bf16x8 xf[4];
            #pragma unroll
            for (int t = 0; t < 4; ++t) xf[t] = *(const bf16x8*)(xb[t] + kk * 64);
            #pragma unroll
            for (int h = 0; h < 2; ++h) {
                const short* wp = wB + (h << 12) + rowoff + (kk << 5);
                bf16x8 wfq = *(const bf16x8*)(wp);
                #pragma unroll
                for (int t = 0; t < 4; ++t) aq[h][t] = MFMA32(wfq, xf[t], aq[h][t]);
                bf16x8 wfk = *(const bf16x8*)(wp + (256 << 8));
                #pragma unroll
                for (int t = 0; t < 4; ++t) ak[h][t] = MFMA32(wfk, xf[t], ak[h][t]);
                bf16x8 wfv = *(const bf16x8*)(wp + (512 << 8));
                #pragma unroll
                for (int t = 0; t < 4; ++t) av[t][h] = MFMA32(xf[t], wfv, av[t][h]);
            }
        }

        // epilogue: bias (+scale on q), pack to K=32 duality fragments; accs die here
        bf16x8 qp[4], kp[4], vp[2][2];
        #pragma unroll
        for (int h = 0; h < 2; ++h) {
            f32x4 bq = *(const f32x4*)(bqkv + (head << 5) + h * 16 + (l4 << 2));
            f32x4 bk = *(const f32x4*)(bqkv + 256 + (head << 5) + h * 16 + (l4 << 2));
            const float bv = bqkv[512 + (head << 5) + h * 16 + l15];
            #pragma unroll
            for (int t = 0; t < 4; ++t)
                #pragma unroll
                for (int rg = 0; rg < 4; ++rg) {
                    qp[t][h * 4 + rg] = f2bf((aq[h][t][rg] + bq[rg]) * 0.17677669529663687f);
                    kp[t][h * 4 + rg] = f2bf(ak[h][t][rg] + bk[rg]);
                    vp[t >> 1][h][(t & 1) * 4 + rg] = f2bf(av[t][h][rg] + bv);
                }
        }

        // attention (per q-tile): S' -> softmax -> P frag -> transposed PV
        #pragma unroll
        for (int qt = 0; qt < 4; ++qt) {
            f32x4 sQ[4];
            #pragma unroll
            for (int t = 0; t < 4; ++t) sQ[t] = (f32x4){0.f, 0.f, 0.f, 0.f};
            #pragma unroll
            for (int t = 0; t < 4; ++t)
                sQ[t] = MFMA32(kp[t], qp[qt], sQ[t]);   // D[kt][q]: col=l15=q

            float m = -1e30f;
            #pragma unroll
            for (int t = 0; t < 4; ++t)
                #pragma unroll
                for (int rg = 0; rg < 4; ++rg) {
                    const bool valid = (t < 3) || ((l4 | rg) == 0);   // kt < 49
                    float v0 = valid ? sQ[t][rg] : -1e30f;
                    sQ[t][rg] = v0;
                    m = fmaxf(m, v0);
                }
            m = fmaxf(m, __shfl_xor(m, 16));
            m = fmaxf(m, __shfl_xor(m, 32));
            float s = 0.f;
            #pragma unroll
            for (int t = 0; t < 4; ++t)
                #pragma unroll
                for (int rg = 0; rg < 4; ++rg) {
                    float e = __expf(sQ[t][rg] - m);
                    sQ[t][rg] = e;
                    s += e;
                }
            s += __shfl_xor(s, 16);
            s += __shfl_xor(s, 32);
            const float inv = 1.f / s;

            bf16x8 pf[2];
            #pragma unroll
            for (int t = 0; t < 4; ++t)
                #pragma unroll
                for (int rg = 0; rg < 4; ++rg)
                    pf[t >> 1][(t & 1) * 4 + rg] = f2bf(sQ[t][rg] * inv);

            #pragma unroll
            for (int h = 0; h < 2; ++h) {
                f32x4 oq = (f32x4){0.f, 0.f, 0.f, 0.f};
                oq = MFMA32(vp[0][h], pf[0], oq);
                oq = MFMA32(vp[1][h], pf[1], oq);
                #pragma unroll
                for (int rg = 0; rg < 4; ++rg) oreg[hh][qt][h][rg] = f2bf(oq[rg]);
            }
        }
    }
    __syncthreads();               // all xw reads done — smem may now be overwritten

    // concat: O[token][256] -> smem
    #pragma unroll
    for (int hh = 0; hh < 2; ++hh) {
        const int head = (hh << 2) + wv4;
        #pragma unroll
        for (int qt = 0; qt < 4; ++qt) {
            const int row = qt * 16 + l15;
            const int colbyte = ((head << 5) + (l4 << 2)) * 2;
            *(bf16x4*)(smem + row * ROWB + colbyte)      = oreg[hh][qt][0];
            *(bf16x4*)(smem + row * ROWB + colbyte + 32) = oreg[hh][qt][1];
        }
    }
    __syncthreads();

    // ---------- Phase 4: proj GEMM (wave: 64 cols in 2 groups) + bias + scatter ----------
    const char* ab[4];
    #pragma unroll
    for (int rt = 0; rt < 4; ++rt) ab[rt] = smem + (rt * 16 + l15) * ROWB + (l4 << 4);
    const int hb = wh * 7 + 3;
    const int wb = ww * 7 + 3;

    #pragma unroll
    for (int g = 0; g < 2; ++g) {
        const int colbase = (wv4 << 6) + (g << 5);
        f32x4 po[2][4];
        #pragma unroll
        for (int c = 0; c < 2; ++c)
            #pragma unroll
            for (int r = 0; r < 4; ++r) po[c][r] = (f32x4){0.f, 0.f, 0.f, 0.f};

        const short* pb[2];
        #pragma unroll
        for (int ct = 0; ct < 2; ++ct)
            pb[ct] = wprojT + ((colbase + (ct << 4) + l15) << 8) + (l4 << 3);

        #pragma unroll
        for (int kk = 0; kk < 8; ++kk) {
            bf16x8 a[4];
            #pragma unroll
            for (int rt = 0; rt < 4; ++rt) a[rt] = *(const bf16x8*)(ab[rt] + kk * 64);
            #pragma unroll
            for (int ct = 0; ct < 2; ++ct) {
                bf16x8 bfr = *(const bf16x8*)(pb[ct] + (kk << 5));
                #pragma unroll
                for (int rt = 0; rt < 4; ++rt)
                    po[ct][rt] = MFMA32(a[rt], bfr, po[ct][rt]);
            }
        }

        #pragma unroll
        for (int ct = 0; ct < 2; ++ct) {
            const int col = colbase + (ct << 4) + l15;
            const float bias = bproj[col];
            #pragma unroll
            for (int rt = 0; rt < 4; ++rt) {
                const int r0 = rt * 16 + (l4 << 2);
                int i = r0 / 7;
                int j = r0 - i * 7;
                #pragma unroll
                for (int rg = 0; rg < 4; ++rg) {
                    const int row = r0 + rg;
                    if (row < 49) {
                        int h  = hb + i; if (h  >= 56) h  -= 56;
                        int wc = wb + j; if (wc >= 56) wc -= 56;
                        out[(((size_t)(b * 56 + h)) * 56 + wc) * 256 + col] = po[ct][rt][rg] + bias;
                    }
                    ++j; if (j == 7) { j = 0; ++i; }
                }
            }
        }
    }
}

extern "C" void kernel_launch(void* const* d_in, const int* in_sizes, int n_in,
                              void* d_out, int out_size, void* d_ws, size_t ws_size,
                              hipStream_t stream) {
    const float* x     = (const float*)d_in[0];
    const float* wqkv  = (const float*)d_in[1];
    const float* bqkv  = (const float*)d_in[2];
    const float* wproj = (const float*)d_in[3];
    const float* bproj = (const float*)d_in[4];
    float* out = (float*)d_out;

    short* wqkvT  = (short*)d_ws;
    short* wprojT = wqkvT + 768 * 256;

    prep_weights<<<dim3(1024), dim3(256), 0, stream>>>(wqkv, wproj, wqkvT, wprojT);
    winattn_fused<<<dim3(2048), dim3(256), 0, stream>>>(x, bqkv, bproj, wqkvT, wprojT, out);
}

// Round 11
// 153.081 us; speedup vs baseline: 1.5767x; 1.5767x over previous
//
#include <hip/hip_runtime.h>
#include <hip/hip_bf16.h>

typedef __attribute__((ext_vector_type(4))) short bf16x4;
typedef __attribute__((ext_vector_type(8))) short bf16x8;
typedef __attribute__((ext_vector_type(4))) float f32x4;

#define MFMA32(A,B,C) __builtin_amdgcn_mfma_f32_16x16x32_bf16(A,B,C,0,0,0)
#define ROWB 528   // LDS row pitch: 512B data + 16B pad -> bank-spread, affine addressing
#define ROWS 49    // only real tokens stored; MFMA row reads clamped to 48

__device__ __forceinline__ short f2bf(float f) {
    __hip_bfloat16 h = __float2bfloat16(f);
    union { __hip_bfloat16 h; short s; } u; u.h = h;
    return u.s;
}

// One-time: transpose+convert weights to bf16.  wqkvT[768][256], wprojT[256][256]
__global__ void prep_weights(const float* __restrict__ wqkv,
                             const float* __restrict__ wproj,
                             short* __restrict__ wqkvT,
                             short* __restrict__ wprojT) {
    const int n = blockIdx.x, k = threadIdx.x;
    if (n < 768) wqkvT[n * 256 + k] = f2bf(wqkv[k * 768 + n]);
    else         wprojT[(n - 768) * 256 + k] = f2bf(wproj[k * 256 + (n - 768)]);
}

// 4-wave block = 1 window; wave owns 2 heads sequentially; sequential h-split QKV passes
// (16 AGPR live) + direct-to-LDS O => total regs ~130 => 3 blocks/CU (LDS 51.7KB/block).
__launch_bounds__(256, 2)
__global__ void winattn_fused(const float* __restrict__ x,
                              const float* __restrict__ bqkv,
                              const float* __restrict__ bproj,
                              const short* __restrict__ wqkvT,
                              const short* __restrict__ wprojT,
                              float* __restrict__ out) {
    __shared__ char smem[2 * ROWS * ROWB];    // 51744 B: xw tile + concat buffer
    char* cbuf = smem + ROWS * ROWB;
    const int tid = threadIdx.x;
    const int wid = blockIdx.x;
    const int b  = wid >> 6;
    const int wh = (wid >> 3) & 7;
    const int ww = wid & 7;

    // ---------- Phase 1: stage rolled window -> LDS bf16, linear [49][ROWB] ----------
    {
        const int r   = tid >> 2;                 // 0..63; only r<49 active
        const int qtr = tid & 3;                  // 64 floats (128B bf16) per thread
        if (r < ROWS) {
            char* dst = smem + r * ROWB + qtr * 128;
            const int i = r / 7, j = r - i * 7;
            int h  = wh * 7 + i + 3; if (h  >= 56) h  -= 56;
            int wc = ww * 7 + j + 3; if (wc >= 56) wc -= 56;
            const float* src = x + (((size_t)(b * 56 + h)) * 56 + wc) * 256 + qtr * 64;
            #pragma unroll
            for (int c = 0; c < 8; ++c) {
                f32x4 f0 = *(const f32x4*)(src + c * 8);
                f32x4 f1 = *(const f32x4*)(src + c * 8 + 4);
                bf16x8 o;
                #pragma unroll
                for (int q = 0; q < 4; ++q) { o[q] = f2bf(f0[q]); o[q + 4] = f2bf(f1[q]); }
                *(bf16x8*)(dst + c * 16) = o;
            }
        }
    }
    __syncthreads();

    const int wv4 = tid >> 6;     // wave 0..3
    const int l   = tid & 63;
    const int l15 = l & 15;
    const int l4  = l >> 4;

    // clamped A-fragment row pointers (rows >48 alias row 48; results masked downstream)
    const char* xb[4];
    #pragma unroll
    for (int t = 0; t < 4; ++t) {
        int row = t * 16 + l15; if (row > 48) row = 48;
        xb[t] = smem + row * ROWB + (l4 << 4);
    }
    const int rowoff = l15 * 256 + (l4 << 3);

    // ---------- Phase 2+3 per head: sequential h-split q/k/v passes -> attention ----------
    #pragma unroll
    for (int hh = 0; hh < 2; ++hh) {
        const int head = (hh << 2) + wv4;
        const short* wqB = wqkvT + ((head << 5) << 8);
        const short* wkB = wqB + (256 << 8);
        const short* wvB = wqB + (512 << 8);

        bf16x8 qp[4], kp[4], vp[2][2];

        // q pass (swapped: D[ch][token])
        #pragma unroll
        for (int h = 0; h < 2; ++h) {
            f32x4 acc[4];
            #pragma unroll
            for (int t = 0; t < 4; ++t) acc[t] = (f32x4){0.f, 0.f, 0.f, 0.f};
            const short* wp = wqB + (h << 12) + rowoff;
            #pragma unroll
            for (int kk = 0; kk < 8; ++kk) {
                bf16x8 wf = *(const bf16x8*)(wp + (kk << 5));
                #pragma unroll
                for (int t = 0; t < 4; ++t) {
                    bf16x8 xf = *(const bf16x8*)(xb[t] + kk * 64);
                    acc[t] = MFMA32(wf, xf, acc[t]);
                }
            }
            f32x4 bq = *(const f32x4*)(bqkv + (head << 5) + h * 16 + (l4 << 2));
            #pragma unroll
            for (int t = 0; t < 4; ++t)
                #pragma unroll
                for (int rg = 0; rg < 4; ++rg)
                    qp[t][h * 4 + rg] = f2bf((acc[t][rg] + bq[rg]) * 0.17677669529663687f);
        }
        // k pass
        #pragma unroll
        for (int h = 0; h < 2; ++h) {
            f32x4 acc[4];
            #pragma unroll
            for (int t = 0; t < 4; ++t) acc[t] = (f32x4){0.f, 0.f, 0.f, 0.f};
            const short* wp = wkB + (h << 12) + rowoff;
            #pragma unroll
            for (int kk = 0; kk < 8; ++kk) {
                bf16x8 wf = *(const bf16x8*)(wp + (kk << 5));
                #pragma unroll
                for (int t = 0; t < 4; ++t) {
                    bf16x8 xf = *(const bf16x8*)(xb[t] + kk * 64);
                    acc[t] = MFMA32(wf, xf, acc[t]);
                }
            }
            f32x4 bk = *(const f32x4*)(bqkv + 256 + (head << 5) + h * 16 + (l4 << 2));
            #pragma unroll
            for (int t = 0; t < 4; ++t)
                #pragma unroll
                for (int rg = 0; rg < 4; ++rg)
                    kp[t][h * 4 + rg] = f2bf(acc[t][rg] + bk[rg]);
        }
        // v pass (unswapped: D[token][ch])
        #pragma unroll
        for (int h = 0; h < 2; ++h) {
            f32x4 acc[4];
            #pragma unroll
            for (int t = 0; t < 4; ++t) acc[t] = (f32x4){0.f, 0.f, 0.f, 0.f};
            const short* wp = wvB + (h << 12) + rowoff;
            #pragma unroll
            for (int kk = 0; kk < 8; ++kk) {
                bf16x8 wf = *(const bf16x8*)(wp + (kk << 5));
                #pragma unroll
                for (int t = 0; t < 4; ++t) {
                    bf16x8 xf = *(const bf16x8*)(xb[t] + kk * 64);
                    acc[t] = MFMA32(xf, wf, acc[t]);
                }
            }
            const float bv = bqkv[512 + (head << 5) + h * 16 + l15];
            #pragma unroll
            for (int t = 0; t < 4; ++t)
                #pragma unroll
                for (int rg = 0; rg < 4; ++rg)
                    vp[t >> 1][h][(t & 1) * 4 + rg] = f2bf(acc[t][rg] + bv);
        }

        // attention (per q-tile): S' -> softmax -> P frag -> transposed PV -> concat LDS
        #pragma unroll
        for (int qt = 0; qt < 4; ++qt) {
            f32x4 sQ[4];
            #pragma unroll
            for (int t = 0; t < 4; ++t) sQ[t] = (f32x4){0.f, 0.f, 0.f, 0.f};
            #pragma unroll
            for (int t = 0; t < 4; ++t)
                sQ[t] = MFMA32(kp[t], qp[qt], sQ[t]);   // D[kt][q]: col=l15=q

            float m = -1e30f;
            #pragma unroll
            for (int t = 0; t < 4; ++t)
                #pragma unroll
                for (int rg = 0; rg < 4; ++rg) {
                    const bool valid = (t < 3) || ((l4 | rg) == 0);   // kt < 49
                    float v0 = valid ? sQ[t][rg] : -1e30f;
                    sQ[t][rg] = v0;
                    m = fmaxf(m, v0);
                }
            m = fmaxf(m, __shfl_xor(m, 16));
            m = fmaxf(m, __shfl_xor(m, 32));
            float s = 0.f;
            #pragma unroll
            for (int t = 0; t < 4; ++t)
                #pragma unroll
                for (int rg = 0; rg < 4; ++rg) {
                    float e = __expf(sQ[t][rg] - m);
                    sQ[t][rg] = e;
                    s += e;
                }
            s += __shfl_xor(s, 16);
            s += __shfl_xor(s, 32);
            const float inv = 1.f / s;

            bf16x8 pf[2];
            #pragma unroll
            for (int t = 0; t < 4; ++t)
                #pragma unroll
                for (int rg = 0; rg < 4; ++rg)
                    pf[t >> 1][(t & 1) * 4 + rg] = f2bf(sQ[t][rg] * inv);

            const int row = qt * 16 + l15;          // token
            #pragma unroll
            for (int h = 0; h < 2; ++h) {
                f32x4 oq = (f32x4){0.f, 0.f, 0.f, 0.f};
                oq = MFMA32(vp[0][h], pf[0], oq);
                oq = MFMA32(vp[1][h], pf[1], oq);
                if (row < ROWS) {
                    bf16x4 ob;
                    #pragma unroll
                    for (int rg = 0; rg < 4; ++rg) ob[rg] = f2bf(oq[rg]);
                    const int colbyte = ((head << 5) + (h << 4) + (l4 << 2)) * 2;
                    *(bf16x4*)(cbuf + row * ROWB + colbyte) = ob;
                }
            }
        }
    }
    __syncthreads();

    // ---------- Phase 4: proj GEMM (wave: 64 cols in 2 groups) + bias + scatter ----------
    const char* ab[4];
    #pragma unroll
    for (int rt = 0; rt < 4; ++rt) {
        int row = rt * 16 + l15; if (row > 48) row = 48;
        ab[rt] = cbuf + row * ROWB + (l4 << 4);
    }
    const int hb = wh * 7 + 3;
    const int wb = ww * 7 + 3;

    #pragma unroll
    for (int g = 0; g < 2; ++g) {
        const int colbase = (wv4 << 6) + (g << 5);
        f32x4 po[2][4];
        #pragma unroll
        for (int c = 0; c < 2; ++c)
            #pragma unroll
            for (int r = 0; r < 4; ++r) po[c][r] = (f32x4){0.f, 0.f, 0.f, 0.f};

        const short* pb[2];
        #pragma unroll
        for (int ct = 0; ct < 2; ++ct)
            pb[ct] = wprojT + ((colbase + (ct << 4) + l15) << 8) + (l4 << 3);

        #pragma unroll
        for (int kk = 0; kk < 8; ++kk) {
            bf16x8 a[4];
            #pragma unroll
            for (int rt = 0; rt < 4; ++rt) a[rt] = *(const bf16x8*)(ab[rt] + kk * 64);
            #pragma unroll
            for (int ct = 0; ct < 2; ++ct) {
                bf16x8 bfr = *(const bf16x8*)(pb[ct] + (kk << 5));
                #pragma unroll
                for (int rt = 0; rt < 4; ++rt)
                    po[ct][rt] = MFMA32(a[rt], bfr, po[ct][rt]);
            }
        }

        #pragma unroll
        for (int ct = 0; ct < 2; ++ct) {
            const int col = colbase + (ct << 4) + l15;
            const float bias = bproj[col];
            #pragma unroll
            for (int rt = 0; rt < 4; ++rt) {
                const int r0 = rt * 16 + (l4 << 2);
                int i = r0 / 7;
                int j = r0 - i * 7;
                #pragma unroll
                for (int rg = 0; rg < 4; ++rg) {
                    const int row = r0 + rg;
                    if (row < 49) {
                        int h  = hb + i; if (h  >= 56) h  -= 56;
                        int wc = wb + j; if (wc >= 56) wc -= 56;
                        out[(((size_t)(b * 56 + h)) * 56 + wc) * 256 + col] = po[ct][rt][rg] + bias;
                    }
                    ++j; if (j == 7) { j = 0; ++i; }
                }
            }
        }
    }
}

extern "C" void kernel_launch(void* const* d_in, const int* in_sizes, int n_in,
                              void* d_out, int out_size, void* d_ws, size_t ws_size,
                              hipStream_t stream) {
    const float* x     = (const float*)d_in[0];
    const float* wqkv  = (const float*)d_in[1];
    const float* bqkv  = (const float*)d_in[2];
    const float* wproj = (const float*)d_in[3];
    const float* bproj = (const float*)d_in[4];
    float* out = (float*)d_out;

    short* wqkvT  = (short*)d_ws;
    short* wprojT = wqkvT + 768 * 256;

    prep_weights<<<dim3(1024), dim3(256), 0, stream>>>(wqkv, wproj, wqkvT, wprojT);
    winattn_fused<<<dim3(2048), dim3(256), 0, stream>>>(x, bqkv, bproj, wqkvT, wprojT, out);
}